// Round 6
// baseline (144.214 us; speedup 1.0000x reference)
//
#include <hip/hip_runtime.h>

#define B_ 32
#define C_ 64
#define N_ 1024
#define T_ 64

typedef __attribute__((ext_vector_type(8))) _Float16 half8;   // 8 f16 = 4 VGPR
typedef __attribute__((ext_vector_type(4))) _Float16 half4;
typedef __attribute__((ext_vector_type(4))) float f32x4;

// ---------------------------------------------------------------------------
// R20: MEASUREMENT ROUND 2. Pipeline = exact R17 (124.49us). Appended: a
// NO-STORE clone of K2 (global stores -> asm volatile sinks; all loads, MFMAs,
// barriers, softmax identical). It writes nothing -> output bit-identical.
//   dur - 124.49 = C = K2 compute-phase time (warm).
//   C in [14,20] -> phase serialization (37 = C + ~20 store drain, no overlap)
//                   -> next: multi-tile pipeline, loads-issued-before-stores.
//   C >= 25      -> latency-bound compute -> attack prologue/barriers.
//   C <= 10      -> write-path inefficiency -> remap store ownership.
// Context: R19 regression (+10.4) showed stores-then-loads in one wave
// serializes on vmcnt FIFO; spill theory dead (32-reg acc didn't help).
// ---------------------------------------------------------------------------

__global__ __launch_bounds__(256) void k_q(const float* __restrict__ x,
                                           const float* __restrict__ alpha,
                                           _Float16* __restrict__ q_h) {
    const int bid = blockIdx.x;
    const int s1  = (bid & 7) * 256 + (bid >> 3);   // bijective, 2048%8==0
    const int b   = s1 >> 6;
    const int n0  = (s1 & 63) * 16;
    const int tid = threadIdx.x;

    const f32x4* xb = (const f32x4*)(x + (size_t)b * C_ * N_ * T_
                                       + (size_t)n0 * T_);
    f32x4 acc = {0.f, 0.f, 0.f, 0.f};
#pragma unroll 4
    for (int c = 0; c < C_; ++c) {
        f32x4 v = __builtin_nontemporal_load(&xb[(size_t)c * (N_ * T_ / 4) + tid]);
        const float ac = alpha[c];
        acc[0] += ac * v[0]; acc[1] += ac * v[1];
        acc[2] += ac * v[2]; acc[3] += ac * v[3];
    }

    half4 h;
#pragma unroll
    for (int j = 0; j < 4; ++j) h[j] = (_Float16)acc[j];   // RTNE cvt
    *(half4*)(q_h + ((size_t)b * N_ + n0) * T_ + (size_t)tid * 4) = h;
}

// STORES=1: real kernel (writes out). STORES=0: identical but sinks values.
template <int STORES>
__global__ __launch_bounds__(512, 4) void k_scores_softmax_t(
        const _Float16* __restrict__ q_h,
        const float* __restrict__ W,
        float* __restrict__ out) {
    const int bid = blockIdx.x;
    const int s   = (bid & 7) * 128 + (bid >> 3);   // bijective, 1024%8==0
    const int b   = s >> 5;
    const int n0  = (s & 31) * 32;
    const int tid  = threadIdx.x;
    const int w    = tid >> 6;                      // wave 0..7 -> cols w*128
    const int lane = tid & 63;
    const int lr   = lane & 15;
    const int lk   = lane >> 4;

    __shared__ float Ws[T_][T_];                    // 16 KB fp32 W
    __shared__ _Float16 qwh[32][72];                // 4.5 KB f16 qw tile
    __shared__ float red[32][8];                    // 1 KB

    // ---- stage W (fp32, coalesced) ----
    {
        const f32x4* Wv = (const f32x4*)W;
        f32x4* Wd = (f32x4*)&Ws[0][0];
        Wd[tid]       = Wv[tid];
        Wd[tid + 512] = Wv[tid + 512];
    }
    __syncthreads();

    // ---- qw tile = q @ W via MFMA, split-precision W (hi+lo f16) ----
    {
        const int tr = w >> 2, tc = w & 3;
        const size_t ar = ((size_t)b * N_ + n0 + tr * 16 + lr) * T_ + lk * 8;
        half8 a0 = *(const half8*)(q_h + ar);        // k = lk*8 .. +7
        half8 a1 = *(const half8*)(q_h + ar + 32);   // k = 32+lk*8 .. +7
        half8 bh0, bh1, bl0, bl1;
#pragma unroll
        for (int j = 0; j < 8; ++j) {
            const float wv0 = Ws[lk * 8 + j][tc * 16 + lr];
            const float wv1 = Ws[lk * 8 + 32 + j][tc * 16 + lr];
            const _Float16 h0 = (_Float16)wv0;
            const _Float16 h1 = (_Float16)wv1;
            bh0[j] = h0; bl0[j] = (_Float16)(wv0 - (float)h0);
            bh1[j] = h1; bl1[j] = (_Float16)(wv1 - (float)h1);
        }
        f32x4 a = {0.f, 0.f, 0.f, 0.f};
        a = __builtin_amdgcn_mfma_f32_16x16x32_f16(a0, bh0, a, 0, 0, 0);
        a = __builtin_amdgcn_mfma_f32_16x16x32_f16(a1, bh1, a, 0, 0, 0);
        a = __builtin_amdgcn_mfma_f32_16x16x32_f16(a0, bl0, a, 0, 0, 0);
        a = __builtin_amdgcn_mfma_f32_16x16x32_f16(a1, bl1, a, 0, 0, 0);
#pragma unroll
        for (int r = 0; r < 4; ++r)
            qwh[tr * 16 + lk * 4 + r][tc * 16 + lr] = (_Float16)a[r];
    }
    __syncthreads();

    // ---- hoist A-frags (qw tile rows) to registers ONCE ----
    half8 af[2][2];
#pragma unroll
    for (int g = 0; g < 2; ++g) {
        af[g][0] = *(const half8*)&qwh[g * 16 + lr][lk * 8];
        af[g][1] = *(const half8*)&qwh[g * 16 + lr][lk * 8 + 32];
    }

    // ---- main MFMA loop: SWAPPED operands -> transposed output tile ----
    f32x4 acc[2][8];
#pragma unroll
    for (int g = 0; g < 2; ++g)
#pragma unroll
        for (int cf = 0; cf < 8; ++cf) acc[g][cf] = {0.f, 0.f, 0.f, 0.f};

    const size_t cb0 = ((size_t)b * N_ + w * 128 + lr) * T_ + lk * 8;
    half8 pb0 = *(const half8*)(q_h + cb0);
    half8 pb1 = *(const half8*)(q_h + cb0 + 32);
#pragma unroll
    for (int cf = 0; cf < 8; ++cf) {
        const half8 bh0 = pb0;
        const half8 bh1 = pb1;
        if (cf < 7) {
            const size_t cbn = cb0 + (size_t)(cf + 1) * 16 * T_;
            pb0 = *(const half8*)(q_h + cbn);
            pb1 = *(const half8*)(q_h + cbn + 32);
        }
#pragma unroll
        for (int g = 0; g < 2; ++g) {
            f32x4 a = acc[g][cf];
            a = __builtin_amdgcn_mfma_f32_16x16x32_f16(bh0, af[g][0], a, 0, 0, 0);
            a = __builtin_amdgcn_mfma_f32_16x16x32_f16(bh1, af[g][1], a, 0, 0, 0);
            acc[g][cf] = a;
        }
    }

    // ---- max-free softmax epilogue, ONE barrier ----
#pragma unroll
    for (int g = 0; g < 2; ++g) {
        float ssum = 0.f;
#pragma unroll
        for (int cf = 0; cf < 8; ++cf) {
#pragma unroll
            for (int r = 0; r < 4; ++r) {
                float e = __expf(acc[g][cf][r]);
                acc[g][cf][r] = e;
                ssum += e;
            }
        }
        ssum += __shfl_xor(ssum, 16);
        ssum += __shfl_xor(ssum, 32);
        if (lane < 16) red[g * 16 + lr][w] = ssum;
    }
    __syncthreads();

#pragma unroll
    for (int g = 0; g < 2; ++g) {
        f32x4 p0 = *(f32x4*)&red[g * 16 + lr][0];
        f32x4 p1 = *(f32x4*)&red[g * 16 + lr][4];
        const float inv = 1.0f / (p0[0] + p0[1] + p0[2] + p0[3] +
                                  p1[0] + p1[1] + p1[2] + p1[3]);
        f32x4* orow = (f32x4*)(out + ((size_t)b * N_ + n0 + g * 16 + lr) * N_
                                   + w * 128 + lk * 4);
#pragma unroll
        for (int cf = 0; cf < 8; ++cf) {
            f32x4 v = acc[g][cf];
            v[0] *= inv; v[1] *= inv; v[2] *= inv; v[3] *= inv;
            if (STORES) {
                orow[cf * 4] = v;                   // dwordx4, 16 B/lane
            } else {
                // rule #17: keep v (and all upstream work) live without memory
                asm volatile("" :: "v"(v[0]), "v"(v[1]), "v"(v[2]), "v"(v[3]));
            }
        }
    }
}

// ---------------------------------------------------------------------------
extern "C" void kernel_launch(void* const* d_in, const int* in_sizes, int n_in,
                              void* d_out, int out_size, void* d_ws, size_t ws_size,
                              hipStream_t stream) {
    const float* x     = (const float*)d_in[0];
    const float* W     = (const float*)d_in[1];
    const float* alpha = (const float*)d_in[2];
    float* out = (float*)d_out;

    _Float16* q_h = (_Float16*)d_ws;                // [B,N,T] f16, 4 MB

    k_q<<<2048, 256, 0, stream>>>(x, alpha, q_h);
    k_scores_softmax_t<1><<<1024, 512, 0, stream>>>(q_h, W, out);
    // MEASUREMENT: no-store clone, writes nothing. dur - 124.49 = compute C.
    k_scores_softmax_t<0><<<1024, 512, 0, stream>>>(q_h, W, out);
}

// Round 7
// 116.924 us; speedup vs baseline: 1.2334x; 1.2334x over previous
//
#include <hip/hip_runtime.h>

#define B_ 32
#define C_ 64
#define N_ 1024
#define T_ 64

typedef __attribute__((ext_vector_type(8))) _Float16 half8;   // 8 f16 = 4 VGPR
typedef __attribute__((ext_vector_type(4))) _Float16 half4;
typedef __attribute__((ext_vector_type(4))) float f32x4;

// ---------------------------------------------------------------------------
// K1: q = sum_c alpha[c]*x[b,c,:,:], stored as ONE fp16 plane. Pure stream,
// NT loads on x (read-once), ~95% read ceiling. At floor — do not touch.
// ---------------------------------------------------------------------------
__global__ __launch_bounds__(256) void k_q(const float* __restrict__ x,
                                           const float* __restrict__ alpha,
                                           _Float16* __restrict__ q_h) {
    const int bid = blockIdx.x;
    const int s1  = (bid & 7) * 256 + (bid >> 3);   // bijective, 2048%8==0
    const int b   = s1 >> 6;
    const int n0  = (s1 & 63) * 16;
    const int tid = threadIdx.x;

    const f32x4* xb = (const f32x4*)(x + (size_t)b * C_ * N_ * T_
                                       + (size_t)n0 * T_);
    f32x4 acc = {0.f, 0.f, 0.f, 0.f};
#pragma unroll 4
    for (int c = 0; c < C_; ++c) {
        f32x4 v = __builtin_nontemporal_load(&xb[(size_t)c * (N_ * T_ / 4) + tid]);
        const float ac = alpha[c];
        acc[0] += ac * v[0]; acc[1] += ac * v[1];
        acc[2] += ac * v[2]; acc[3] += ac * v[3];
    }

    half4 h;
#pragma unroll
    for (int j = 0; j < 4; ++j) h[j] = (_Float16)acc[j];   // RTNE cvt
    *(half4*)(q_h + ((size_t)b * N_ + n0) * T_ + (size_t)tid * 4) = h;
}

// ---------------------------------------------------------------------------
// K2 (R21): store-streaming 4-tile structure. R20 measured K2 = 19.7us
// compute + 17.2us store drain, FULLY SERIAL (stores all at block end;
// __syncthreads drains vmcnt; R19 showed loads-after-stores FIFO poison).
// Fix exploits: B-stripes are independent of the row-tile -> load all 16
// frags into registers ONCE (64 VGPR), reuse across 4 row-tiles of 16.
// Per-tile loop then has ZERO global loads (af via LDS/lgkmcnt, MFMA regs),
// so tile g's stores have no vmcnt consumers -> tile g+1 compute overlaps
// tile g's drain. In-loop barrier is LDS-only (lgkmcnt(0) + raw s_barrier,
// 8-phase-template pattern) so it does NOT drain stores. red[2] dbuf makes
// 1 barrier/tile race-free. 512 blocks x 512 thr (2/CU), 64 rows/block.
// Predict K2 ~22-26 (drain-bound, compute hidden), total ~109-116.
// ---------------------------------------------------------------------------
__global__ __launch_bounds__(512, 4) void k_scores_softmax(
        const _Float16* __restrict__ q_h,
        const float* __restrict__ W,
        float* __restrict__ out) {
    const int bid = blockIdx.x;
    const int s   = (bid & 7) * 64 + (bid >> 3);    // bijective, 512%8==0
    const int b   = s >> 4;                         // same b<->XCD map as K1
    const int n0  = (s & 15) * 64;                  // 64-row tile base
    const int tid  = threadIdx.x;
    const int w    = tid >> 6;                      // wave 0..7 -> cols w*128
    const int lane = tid & 63;
    const int lr   = lane & 15;
    const int lk   = lane >> 4;

    __shared__ float Ws[T_][T_];                    // 16 KB fp32 W
    __shared__ _Float16 qwh[64][72];                // 9 KB f16 qw tile (64 rows)
    __shared__ float red[2][16][8];                 // 1 KB, double-buffered

    // ---- stage W (fp32, coalesced) ----
    {
        const f32x4* Wv = (const f32x4*)W;
        f32x4* Wd = (f32x4*)&Ws[0][0];
        Wd[tid]       = Wv[tid];
        Wd[tid + 512] = Wv[tid + 512];
    }
    __syncthreads();

    // ---- qw (64 rows) = q @ W via MFMA, split-precision W (hi+lo f16) ----
    // wave w: col-block tc = w&3; row-blocks tr0, tr0+1. W-frags shared.
    {
        const int tc  = w & 3;
        const int tr0 = (w >> 2) * 2;
        half8 bh0, bh1, bl0, bl1;
#pragma unroll
        for (int j = 0; j < 8; ++j) {
            const float wv0 = Ws[lk * 8 + j][tc * 16 + lr];
            const float wv1 = Ws[lk * 8 + 32 + j][tc * 16 + lr];
            const _Float16 h0 = (_Float16)wv0;
            const _Float16 h1 = (_Float16)wv1;
            bh0[j] = h0; bl0[j] = (_Float16)(wv0 - (float)h0);
            bh1[j] = h1; bl1[j] = (_Float16)(wv1 - (float)h1);
        }
#pragma unroll
        for (int i = 0; i < 2; ++i) {
            const int tr = tr0 + i;
            const size_t ar = ((size_t)b * N_ + n0 + tr * 16 + lr) * T_ + lk * 8;
            half8 a0 = *(const half8*)(q_h + ar);    // k = lk*8 .. +7
            half8 a1 = *(const half8*)(q_h + ar + 32);
            f32x4 a = {0.f, 0.f, 0.f, 0.f};
            a = __builtin_amdgcn_mfma_f32_16x16x32_f16(a0, bh0, a, 0, 0, 0);
            a = __builtin_amdgcn_mfma_f32_16x16x32_f16(a1, bh1, a, 0, 0, 0);
            a = __builtin_amdgcn_mfma_f32_16x16x32_f16(a0, bl0, a, 0, 0, 0);
            a = __builtin_amdgcn_mfma_f32_16x16x32_f16(a1, bl1, a, 0, 0, 0);
            // C layout: col = lr, row = lk*4 + r
#pragma unroll
            for (int r = 0; r < 4; ++r)
                qwh[tr * 16 + lk * 4 + r][tc * 16 + lr] = (_Float16)a[r];
        }
    }

    // ---- load ALL 16 B-stripe frags ONCE (tile-independent!) ----
    half8 bst0[8], bst1[8];                         // 64 VGPR, live whole loop
    {
        const size_t cb0 = ((size_t)b * N_ + w * 128 + lr) * T_ + lk * 8;
#pragma unroll
        for (int cf = 0; cf < 8; ++cf) {
            bst0[cf] = *(const half8*)(q_h + cb0 + (size_t)cf * 16 * T_);
            bst1[cf] = *(const half8*)(q_h + cb0 + (size_t)cf * 16 * T_ + 32);
        }
    }
    __syncthreads();                                // qwh ready (drains loads too)

    float* const obase = out + ((size_t)b * N_ + n0 + lr) * N_ + w * 128 + lk * 4;

    // ---- 4 row-tiles; tile g's stores drain under tile g+1's compute ----
#pragma unroll 1
    for (int g = 0; g < 4; ++g) {
        half8 af0 = *(const half8*)&qwh[g * 16 + lr][lk * 8];
        half8 af1 = *(const half8*)&qwh[g * 16 + lr][lk * 8 + 32];

        f32x4 acc[8];
#pragma unroll
        for (int cf = 0; cf < 8; ++cf) {
            // swapped operands: lane owns out row n0+g*16+lr,
            // reg r = col w*128+cf*16+lk*4+r (4 consecutive floats)
            f32x4 a = {0.f, 0.f, 0.f, 0.f};
            a = __builtin_amdgcn_mfma_f32_16x16x32_f16(bst0[cf], af0, a, 0, 0, 0);
            a = __builtin_amdgcn_mfma_f32_16x16x32_f16(bst1[cf], af1, a, 0, 0, 0);
            acc[cf] = a;
        }

        // ---- max-free softmax for these 16 rows ----
        float ssum = 0.f;
#pragma unroll
        for (int cf = 0; cf < 8; ++cf) {
#pragma unroll
            for (int r = 0; r < 4; ++r) {
                float e = __expf(acc[cf][r]);
                acc[cf][r] = e;
                ssum += e;
            }
        }
        ssum += __shfl_xor(ssum, 16);               // sum across lk group
        ssum += __shfl_xor(ssum, 32);
        if (lane < 16) red[g & 1][lr][w] = ssum;

        // LDS-ONLY barrier: lgkmcnt drained, vmcnt NOT -> prior tile's global
        // stores keep draining under this barrier and the next tile's compute.
        asm volatile("s_waitcnt lgkmcnt(0)" ::: "memory");
        __builtin_amdgcn_s_barrier();
        asm volatile("" ::: "memory");

        f32x4 p0 = *(f32x4*)&red[g & 1][lr][0];
        f32x4 p1 = *(f32x4*)&red[g & 1][lr][4];
        const float inv = 1.0f / (p0[0] + p0[1] + p0[2] + p0[3] +
                                  p1[0] + p1[1] + p1[2] + p1[3]);
        f32x4* orow = (f32x4*)(obase + (size_t)g * 16 * N_);
#pragma unroll
        for (int cf = 0; cf < 8; ++cf) {
            f32x4 v = acc[cf];
            v[0] *= inv; v[1] *= inv; v[2] *= inv; v[3] *= inv;
            orow[cf * 4] = v;                       // dwordx4; no vmcnt consumer
        }
    }
}

// ---------------------------------------------------------------------------
extern "C" void kernel_launch(void* const* d_in, const int* in_sizes, int n_in,
                              void* d_out, int out_size, void* d_ws, size_t ws_size,
                              hipStream_t stream) {
    const float* x     = (const float*)d_in[0];
    const float* W     = (const float*)d_in[1];
    const float* alpha = (const float*)d_in[2];
    float* out = (float*)d_out;

    _Float16* q_h = (_Float16*)d_ws;                // [B,N,T] f16, 4 MB

    k_q<<<2048, 256, 0, stream>>>(x, alpha, q_h);
    k_scores_softmax<<<512, 512, 0, stream>>>(q_h, W, out);
}